// Round 5
// baseline (234.983 us; speedup 1.0000x reference)
//
#include <hip/hip_runtime.h>

// IDWT reconstruction, LDS-staged tiles: each input byte crosses
// L2/LLC exactly ONCE (previous versions had 4x read amplification;
// 671 MB through LLC @ ~10 TB/s was the invariant wall across three
// structurally different register-level kernels).
//
// x: (B=16, L=32768, 64) f32, channels [0,32)=A, [32,64)=D.
// out: (16, 2L, 32) f32.
// out[b, 2p,   c] = sum_t lo[2t+1]*A[p-1+t][c] + hi[2t+1]*D[p-1+t][c]
// out[b, 2p+1, c] = sum_t lo[2t  ]*A[p-1+t][c] + hi[2t  ]*D[p-1+t][c]
//
// WG = 256 threads, tile = 64 p-positions. Stage rows p0-1..p0+65
// (67 rows x 256 B = 17 KB, contiguous in global) into LDS once,
// then each thread computes 4 consecutive p for one (parity, c4):
// 7-row register window, 14 ds_read_b128 per thread (even 8-words/bank).

#define B_    16
#define L_    32768
#define CIN_  64
#define COUT_ 32
#define TP    64          // p-positions per workgroup
#define NR    (TP + 3)    // 67 staged rows
#define LDSW  CIN_        // row stride in floats (dense; b128 reads are bank-even)

typedef float vfloat4 __attribute__((ext_vector_type(4)));

__global__ __launch_bounds__(256) void idwt_kernel(
    const float* __restrict__ x,
    const float* __restrict__ rec_lo,
    const float* __restrict__ rec_hi,
    float* __restrict__ out)
{
    __shared__ float tile[NR * LDSW];   // 17,152 B

    const int wg = blockIdx.x;
    const int b  = wg >> 9;             // L_/TP = 512 tiles per batch
    const int p0 = (wg & 511) * TP;

    const float* xb = x + b * (L_ * CIN_);

    // ---- stage: 67 rows, j = p0-1 .. p0+65 (contiguous, each byte once) ----
    for (int idx = threadIdx.x; idx < NR * (CIN_ / 4); idx += 256) {
        const int r  = idx >> 4;        // LDS row 0..66
        const int fc = idx & 15;        // float4 within row
        const int j  = p0 - 1 + r;      // global row
        vfloat4 v = {0.f, 0.f, 0.f, 0.f};
        if ((unsigned)j < (unsigned)L_)
            v = *(const vfloat4*)(xb + j * CIN_ + fc * 4);
        *(vfloat4*)(&tile[r * LDSW + fc * 4]) = v;
    }
    __syncthreads();

    // ---- compute: thread = (pg, parity, g); 4 consecutive p each ----
    const int t_     = threadIdx.x;
    const int g      = t_ & 7;          // channel float4
    const int parity = (t_ >> 3) & 1;   // 0: even row, 1: odd row
    const int pg     = t_ >> 4;         // 0..15
    const int pl0    = pg * 4;          // first p (tile-local)

    // even rows use taps 2t+1, odd rows taps 2t (wave-uniform s_loads)
    float fA[4], fD[4];
#pragma unroll
    for (int t = 0; t < 4; ++t) {
        fA[t] = parity ? rec_lo[2 * t] : rec_lo[2 * t + 1];
        fD[t] = parity ? rec_hi[2 * t] : rec_hi[2 * t + 1];
    }

    // 7-row register window: LDS row pl0+r holds global row p0+pl0-1+r
    float Ar[7][4], Dr[7][4];
#pragma unroll
    for (int r = 0; r < 7; ++r) {
        const float* rp = &tile[(pl0 + r) * LDSW + (g << 2)];
        const vfloat4 a = *(const vfloat4*)(rp);
        const vfloat4 d = *(const vfloat4*)(rp + COUT_);
        Ar[r][0] = a.x; Ar[r][1] = a.y; Ar[r][2] = a.z; Ar[r][3] = a.w;
        Dr[r][0] = d.x; Dr[r][1] = d.y; Dr[r][2] = d.z; Dr[r][3] = d.w;
    }

    float* ob = out + (b * (2 * L_) + 2 * (p0 + pl0) + parity) * COUT_ + (g << 2);

#pragma unroll
    for (int i = 0; i < 4; ++i) {
        float acc[4] = {0.f, 0.f, 0.f, 0.f};
#pragma unroll
        for (int t = 0; t < 4; ++t)
#pragma unroll
            for (int c = 0; c < 4; ++c)
                acc[c] = fmaf(fA[t], Ar[i + t][c], fmaf(fD[t], Dr[i + t][c], acc[c]));
        vfloat4 v = {acc[0], acc[1], acc[2], acc[3]};
        __builtin_nontemporal_store(v, (vfloat4*)(ob + i * 2 * COUT_));
    }
}

extern "C" void kernel_launch(void* const* d_in, const int* in_sizes, int n_in,
                              void* d_out, int out_size, void* d_ws, size_t ws_size,
                              hipStream_t stream) {
    const float* x      = (const float*)d_in[0];
    const float* rec_lo = (const float*)d_in[1];
    const float* rec_hi = (const float*)d_in[2];
    float* out = (float*)d_out;

    const int blocks = B_ * (L_ / TP);  // 16 * 512 = 8192 WGs
    idwt_kernel<<<blocks, 256, 0, stream>>>(x, rec_lo, rec_hi, out);
}